// Round 11
// baseline (42.180 us; speedup 1.0000x reference)
//
#include <hip/hip_runtime.h>
#include <hip/hip_cooperative_groups.h>
#include <math.h>

// ---------------------------------------------------------------------------
// FashionNetLoss: 3-scale YOLO-ish loss.
//  * obj focal loss is a mean over ALL cells, but target is 0 except at the
//    512 occupied cells per scale -> sum focal(x,0) over all cells + per-
//    target correction focal(x,t)-focal(x,0).
//  * box & cls losses only touch the 512 target cells per scale; npos==512.
//
// R10 post-mortem: 2-node shape is at its floor (609 vs 156 blocks: 14.77 vs
// 14.81us — invariant). Residual = per-node dispatch overhead. R7/R9 fusion
// failures were hand-rolled publish chains (same-line RMW ~13ns each + per-
// block vmcnt(0) round-trips); the MINIMAL barrier (plain stores + one
// arrive per block) is what the runtime's cooperative grid.sync() gives.
// R11: ONE cooperative node. R10's exact partition + math; plain-store
// slots; this_grid().sync(); block 0 finalizes (reads 156 float4 = 2.4KB).
// Grid = 156 blocks x 256 thr — trivially co-resident on 256 CUs.
//
// Block map: [0,6) box+cls (s=wid>>1), [6,106) sweep s0 (2048 f4/blk),
//            [106,131) sweep s1 (2048 f4/blk), [131,156) sweep s2 (512).
// Slot: ws4[wid] = {box, corr, cls, 0} box blocks, {focal,0,0,0} sweep.
// ---------------------------------------------------------------------------

namespace cg = cooperative_groups;

#define NBLK_BOX 6
#define NBLK_S0 100    // 2048 float4/block, 8/thread
#define NBLK_S1 25     // 2048 float4/block, 8/thread
#define NBLK_S2 25     // 512 float4/block, 2/thread
#define NWORK (NBLK_BOX + NBLK_S0 + NBLK_S1 + NBLK_S2)   // 156

namespace {
// exact path (box blocks only)
__device__ __forceinline__ float bce_logits(float x, float t) {
    return fmaxf(x, 0.0f) - x * t + log1pf(expf(-fabsf(x)));
}
__device__ __forceinline__ float focal_term(float x, float t) {
    float b = bce_logits(x, t);
    float pt = expf(-b);
    float om = fmaxf(1.0f - pt, 0.0f);
    return 0.25f * om * sqrtf(om) * b;   // alpha=0.25, gamma=1.5
}
// fast path (sweep + cls): v_exp_f32 / v_log_f32 based
__device__ __forceinline__ float softplus_neg(float u) {  // log1p(exp(u)), u<=0
    return __logf(1.0f + __expf(u));
}
__device__ __forceinline__ float bce_fast(float x, float t) {
    return fmaxf(x, 0.0f) - x * t + softplus_neg(-fabsf(x));
}
__device__ __forceinline__ float focal0_fast(float x) {   // focal(x, 0)
    float b = fmaxf(x, 0.0f) + softplus_neg(-fabsf(x));
    float pt = __expf(-b);
    float om = fmaxf(1.0f - pt, 0.0f);
    return 0.25f * om * sqrtf(om) * b;
}
} // namespace

__global__ void __launch_bounds__(256) fnl_coop(
    const float* __restrict__ p0, const float* __restrict__ p1,
    const float* __restrict__ p2, const float* __restrict__ tg,
    float4* __restrict__ ws4, float* __restrict__ out) {
    __shared__ float sm0[4], sm1[4], sm2[4];
    const int wid = blockIdx.x;

    float v0 = 0.0f, v1 = 0.0f, v2 = 0.0f;

    if (wid < NBLK_BOX) {
        // ---- box + obj-corr + cls: one thread per (target,scale) ----------
        const float* const ps[3] = {p0, p1, p2};
        const int gss[3] = {160, 80, 40};
        int gid = wid * 256 + threadIdx.x;           // [0,1536)
        int s = gid >> 9;                            // block-uniform (wid>>1)
        int t = gid & 511;

        const float bi  = tg[t * 6 + 0];
        const float clf = tg[t * 6 + 1];
        const float cx  = tg[t * 6 + 2];
        const float cy  = tg[t * 6 + 3];
        const float w   = tg[t * 6 + 4];
        const float h   = tg[t * 6 + 5];
        const int b = (int)bi;
        const int cls = (int)clf;

        const int gs = gss[s];
        const float fgs = (float)gs;
        float cxs = cx * fgs, cys = cy * fgs;
        int gi = (int)floorf(cxs); gi = min(max(gi, 0), gs - 1);
        int gj = (int)floorf(cys); gj = min(max(gj, 0), gs - 1);
        const float tx = cxs - (float)gi;
        const float ty = cys - (float)gj;
        const float tw = w * fgs;
        const float th = h * fgs;

        const int hw = gs * gs;
        const float* base = ps[s] + (size_t)b * 18 * hw + (size_t)gj * gs + gi;
        // 18 independent channel loads — one latency round.
        float pr[18];
        #pragma unroll
        for (int ch = 0; ch < 18; ++ch) pr[ch] = base[(size_t)ch * hw];

        const float px = 1.0f / (1.0f + expf(-pr[0]));
        const float py = 1.0f / (1.0f + expf(-pr[1]));
        const float pw = pr[2];
        const float ph = pr[3];

        const float eps = 1e-7f;
        float px1 = px - pw * 0.5f, px2 = px + pw * 0.5f;
        float py1 = py - ph * 0.5f, py2 = py + ph * 0.5f;
        float tx1 = tx - tw * 0.5f, tx2 = tx + tw * 0.5f;
        float ty1 = ty - th * 0.5f, ty2 = ty + th * 0.5f;
        float iw = fmaxf(fminf(px2, tx2) - fmaxf(px1, tx1), 0.0f);
        float ih = fmaxf(fminf(py2, ty2) - fmaxf(py1, ty1), 0.0f);
        float inter = iw * ih;
        float uni = pw * ph + tw * th - inter + eps;
        float iou = inter / uni;
        float ew = fmaxf(fmaxf(px2, tx2) - fminf(px1, tx1), 0.0f);
        float eh = fmaxf(fmaxf(py2, ty2) - fminf(py1, ty1), 0.0f);
        float c2 = ew * ew + eh * eh + eps;
        float rho2 = (px - tx) * (px - tx) + (py - ty) * (py - ty);
        const float four_over_pi2 = 0.405284734569351085775517852f;
        float dat = atanf(tw / (th + eps)) - atanf(pw / (ph + eps));
        float v = four_over_pi2 * dat * dat;
        float alpha = v / (1.0f - iou + v + eps);
        float ciou = iou - (rho2 / c2 + v * alpha);

        v0 = 1.0f - ciou;                                     // box
        float tobj = fmaxf(ciou, 0.0f);
        v1 = focal_term(pr[4], tobj) - focal_term(pr[4], 0.0f);  // obj corr
        #pragma unroll
        for (int k = 0; k < 13; ++k) {                        // cls sum
            float tc = (k == cls) ? 0.95f : 0.0f;
            v2 += bce_fast(pr[5 + k], tc);
        }
    } else if (wid < NBLK_BOX + NBLK_S0 + NBLK_S1) {
        // ---- focal(x,0) sweep s0/s1: 2048 float4/block, 8/thread ----------
        const float* p;
        int hw4, chunk;
        if (wid < NBLK_BOX + NBLK_S0) { p = p0; hw4 = 6400; chunk = wid - NBLK_BOX; }
        else                          { p = p1; hw4 = 1600; chunk = wid - NBLK_BOX - NBLK_S0; }
        int j0 = chunk * 2048 + threadIdx.x;         // float4 idx in scale
        #pragma unroll
        for (int r = 0; r < 8; ++r) {
            int idx = j0 + r * 256;
            int b = idx / hw4;
            int pos4 = idx - b * hw4;
            int hw = hw4 * 4;
            const float4* src = reinterpret_cast<const float4*>(
                p + (size_t)b * 18 * hw + (size_t)4 * hw);
            float4 x = src[pos4];
            v0 += focal0_fast(x.x) + focal0_fast(x.y) +
                  focal0_fast(x.z) + focal0_fast(x.w);
        }
    } else {
        // ---- focal(x,0) sweep s2: 512 float4/block, 2/thread --------------
        int chunk = wid - NBLK_BOX - NBLK_S0 - NBLK_S1;
        const int hw4 = 400, hw = 1600;
        int j0 = chunk * 512 + threadIdx.x;
        #pragma unroll
        for (int r = 0; r < 2; ++r) {
            int idx = j0 + r * 256;
            int b = idx / hw4;
            int pos4 = idx - b * hw4;
            const float4* src = reinterpret_cast<const float4*>(
                p2 + (size_t)b * 18 * hw + (size_t)4 * hw);
            float4 x = src[pos4];
            v0 += focal0_fast(x.x) + focal0_fast(x.y) +
                  focal0_fast(x.z) + focal0_fast(x.w);
        }
    }

    // ---- block reduce, one coalesced float4 store (plain, no atomics) -----
    for (int off = 32; off; off >>= 1) {
        v0 += __shfl_down(v0, off);
        v1 += __shfl_down(v1, off);
        v2 += __shfl_down(v2, off);
    }
    if ((threadIdx.x & 63) == 0) {
        sm0[threadIdx.x >> 6] = v0;
        sm1[threadIdx.x >> 6] = v1;
        sm2[threadIdx.x >> 6] = v2;
    }
    __syncthreads();
    if (threadIdx.x == 0) {
        float4 slot;
        slot.x = sm0[0] + sm0[1] + sm0[2] + sm0[3];
        slot.y = sm1[0] + sm1[1] + sm1[2] + sm1[3];
        slot.z = sm2[0] + sm2[1] + sm2[2] + sm2[3];
        slot.w = 0.0f;
        ws4[wid] = slot;
    }

    // ---- grid-wide barrier (runtime-managed, release/acquire) -------------
    cg::this_grid().sync();
    if (blockIdx.x != 0) return;

    // ---- block 0 finalizes: 156 float4 = 2.4KB coalesced ------------------
    float a[12];   // [s*4 + {0:focal,1:box,2:cls,3:corr}]
    #pragma unroll
    for (int j = 0; j < 12; ++j) a[j] = 0.0f;

    int i = threadIdx.x;
    if (i < NWORK) {
        float4 v = ws4[i];
        if (i < NBLK_BOX) {
            int s = i >> 1;
            a[s * 4 + 1] += v.x;
            a[s * 4 + 3] += v.y;
            a[s * 4 + 2] += v.z;
        } else if (i < NBLK_BOX + NBLK_S0) {
            a[0 * 4 + 0] += v.x;
        } else if (i < NBLK_BOX + NBLK_S0 + NBLK_S1) {
            a[1 * 4 + 0] += v.x;
        } else {
            a[2 * 4 + 0] += v.x;
        }
    }

    __shared__ float red[12];
    if (threadIdx.x < 12) red[threadIdx.x] = 0.0f;
    __syncthreads();
    #pragma unroll
    for (int j = 0; j < 12; ++j) {
        float v = a[j];
        for (int off = 32; off; off >>= 1) v += __shfl_down(v, off);
        if ((threadIdx.x & 63) == 0) atomicAdd(&red[j], v);   // LDS atomic
    }
    __syncthreads();

    if (threadIdx.x == 0) {
        const float cells[3] = {819200.0f, 204800.0f, 51200.0f};
        const float npos = 512.0f;
        float lb = 0.0f, lo = 0.0f, lc = 0.0f;
        for (int s = 0; s < 3; ++s) {
            lb += red[s * 4 + 1] / npos;
            lo += (red[s * 4 + 0] + red[s * 4 + 3]) / cells[s];
            lc += red[s * 4 + 2] / (npos * 13.0f);
        }
        out[0] = 5.0f * lb + 1.0f * lo + 0.5f * lc;
        out[1] = lb;
        out[2] = lo;
        out[3] = lc;
    }
}

extern "C" void kernel_launch(void* const* d_in, const int* in_sizes, int n_in,
                              void* d_out, int out_size, void* d_ws, size_t ws_size,
                              hipStream_t stream) {
    const float* p0 = (const float*)d_in[0];
    const float* p1 = (const float*)d_in[1];
    const float* p2 = (const float*)d_in[2];
    const float* tg = (const float*)d_in[3];
    float4* ws4 = (float4*)d_ws;
    float* out = (float*)d_out;

    void* args[] = {(void*)&p0, (void*)&p1, (void*)&p2, (void*)&tg,
                    (void*)&ws4, (void*)&out};
    hipLaunchCooperativeKernel((void*)fnl_coop, dim3(NWORK), dim3(256),
                               args, 0, stream);
}

// Round 12
// 14.943 us; speedup vs baseline: 2.8227x; 2.8227x over previous
//
#include <hip/hip_runtime.h>
#include <math.h>

// ---------------------------------------------------------------------------
// FashionNetLoss: 3-scale YOLO-ish loss. FINAL (R10 shape, reverted from the
// R11 cooperative experiment which regressed to 42us).
//
// Structure: 2 nodes — fnl_main (156 blocks, block-private float4 slot
// stores, zero global atomics) + fnl_finalize (1 block). ~4us work + ~10us
// fixed 2-node dispatch overhead = ~14.8us. Fusion disproven 3 ways:
//   R7 spin consumer +4.5us, R9 arrival-tree +4.9us, R11 coop grid.sync
//   +27us (runtime barrier does cross-XCD L2 maintenance per sync).
// Key mechanisms (each validated by A/B):
//  * obj focal = sum focal(x,0) over all 1.07M cells + 512-target correction
//    focal(x,t)-focal(x,0); box/cls touch only target cells; npos==512.
//  * zero same-line global atomics (R5: ~13ns/RMW serialized, was 15us).
//  * fast __expf/__logf softplus in sweep+cls (R6: -2.4us); box path exact.
//  * block-private slots + 1-block finalize reading 156 float4 (2.4KB).
//
// Block map: [0,6) box+cls (s=wid>>1), [6,106) sweep s0 (2048 f4/blk),
//            [106,131) sweep s1 (2048 f4/blk), [131,156) sweep s2 (512).
// Slot: ws4[wid] = {box, corr, cls, 0} box blocks, {focal,0,0,0} sweep.
// ---------------------------------------------------------------------------

#define NBLK_BOX 6
#define NBLK_S0 100    // 2048 float4/block, 8/thread
#define NBLK_S1 25     // 2048 float4/block, 8/thread
#define NBLK_S2 25     // 512 float4/block, 2/thread
#define NWORK (NBLK_BOX + NBLK_S0 + NBLK_S1 + NBLK_S2)   // 156

namespace {
// exact path (box blocks only)
__device__ __forceinline__ float bce_logits(float x, float t) {
    return fmaxf(x, 0.0f) - x * t + log1pf(expf(-fabsf(x)));
}
__device__ __forceinline__ float focal_term(float x, float t) {
    float b = bce_logits(x, t);
    float pt = expf(-b);
    float om = fmaxf(1.0f - pt, 0.0f);
    return 0.25f * om * sqrtf(om) * b;   // alpha=0.25, gamma=1.5
}
// fast path (sweep + cls): v_exp_f32 / v_log_f32 based
__device__ __forceinline__ float softplus_neg(float u) {  // log1p(exp(u)), u<=0
    return __logf(1.0f + __expf(u));
}
__device__ __forceinline__ float bce_fast(float x, float t) {
    return fmaxf(x, 0.0f) - x * t + softplus_neg(-fabsf(x));
}
__device__ __forceinline__ float focal0_fast(float x) {   // focal(x, 0)
    float b = fmaxf(x, 0.0f) + softplus_neg(-fabsf(x));
    float pt = __expf(-b);
    float om = fmaxf(1.0f - pt, 0.0f);
    return 0.25f * om * sqrtf(om) * b;
}
} // namespace

__global__ void __launch_bounds__(256) fnl_main(
    const float* __restrict__ p0, const float* __restrict__ p1,
    const float* __restrict__ p2, const float* __restrict__ tg,
    float4* __restrict__ ws4) {
    __shared__ float sm0[4], sm1[4], sm2[4];
    const int wid = blockIdx.x;

    float v0 = 0.0f, v1 = 0.0f, v2 = 0.0f;

    if (wid < NBLK_BOX) {
        // ---- box + obj-corr + cls: one thread per (target,scale) ----------
        const float* const ps[3] = {p0, p1, p2};
        const int gss[3] = {160, 80, 40};
        int gid = wid * 256 + threadIdx.x;           // [0,1536)
        int s = gid >> 9;                            // block-uniform (wid>>1)
        int t = gid & 511;

        const float bi  = tg[t * 6 + 0];
        const float clf = tg[t * 6 + 1];
        const float cx  = tg[t * 6 + 2];
        const float cy  = tg[t * 6 + 3];
        const float w   = tg[t * 6 + 4];
        const float h   = tg[t * 6 + 5];
        const int b = (int)bi;
        const int cls = (int)clf;

        const int gs = gss[s];
        const float fgs = (float)gs;
        float cxs = cx * fgs, cys = cy * fgs;
        int gi = (int)floorf(cxs); gi = min(max(gi, 0), gs - 1);
        int gj = (int)floorf(cys); gj = min(max(gj, 0), gs - 1);
        const float tx = cxs - (float)gi;
        const float ty = cys - (float)gj;
        const float tw = w * fgs;
        const float th = h * fgs;

        const int hw = gs * gs;
        const float* base = ps[s] + (size_t)b * 18 * hw + (size_t)gj * gs + gi;
        // 18 independent channel loads — one latency round.
        float pr[18];
        #pragma unroll
        for (int ch = 0; ch < 18; ++ch) pr[ch] = base[(size_t)ch * hw];

        const float px = 1.0f / (1.0f + expf(-pr[0]));
        const float py = 1.0f / (1.0f + expf(-pr[1]));
        const float pw = pr[2];
        const float ph = pr[3];

        const float eps = 1e-7f;
        float px1 = px - pw * 0.5f, px2 = px + pw * 0.5f;
        float py1 = py - ph * 0.5f, py2 = py + ph * 0.5f;
        float tx1 = tx - tw * 0.5f, tx2 = tx + tw * 0.5f;
        float ty1 = ty - th * 0.5f, ty2 = ty + th * 0.5f;
        float iw = fmaxf(fminf(px2, tx2) - fmaxf(px1, tx1), 0.0f);
        float ih = fmaxf(fminf(py2, ty2) - fmaxf(py1, ty1), 0.0f);
        float inter = iw * ih;
        float uni = pw * ph + tw * th - inter + eps;
        float iou = inter / uni;
        float ew = fmaxf(fmaxf(px2, tx2) - fminf(px1, tx1), 0.0f);
        float eh = fmaxf(fmaxf(py2, ty2) - fminf(py1, ty1), 0.0f);
        float c2 = ew * ew + eh * eh + eps;
        float rho2 = (px - tx) * (px - tx) + (py - ty) * (py - ty);
        const float four_over_pi2 = 0.405284734569351085775517852f;
        float dat = atanf(tw / (th + eps)) - atanf(pw / (ph + eps));
        float v = four_over_pi2 * dat * dat;
        float alpha = v / (1.0f - iou + v + eps);
        float ciou = iou - (rho2 / c2 + v * alpha);

        v0 = 1.0f - ciou;                                     // box
        float tobj = fmaxf(ciou, 0.0f);
        v1 = focal_term(pr[4], tobj) - focal_term(pr[4], 0.0f);  // obj corr
        #pragma unroll
        for (int k = 0; k < 13; ++k) {                        // cls sum
            float tc = (k == cls) ? 0.95f : 0.0f;
            v2 += bce_fast(pr[5 + k], tc);
        }
    } else if (wid < NBLK_BOX + NBLK_S0 + NBLK_S1) {
        // ---- focal(x,0) sweep s0/s1: 2048 float4/block, 8/thread ----------
        const float* p;
        int hw4, chunk;
        if (wid < NBLK_BOX + NBLK_S0) { p = p0; hw4 = 6400; chunk = wid - NBLK_BOX; }
        else                          { p = p1; hw4 = 1600; chunk = wid - NBLK_BOX - NBLK_S0; }
        int j0 = chunk * 2048 + threadIdx.x;         // float4 idx in scale
        #pragma unroll
        for (int r = 0; r < 8; ++r) {
            int idx = j0 + r * 256;
            int b = idx / hw4;
            int pos4 = idx - b * hw4;
            int hw = hw4 * 4;
            const float4* src = reinterpret_cast<const float4*>(
                p + (size_t)b * 18 * hw + (size_t)4 * hw);
            float4 x = src[pos4];
            v0 += focal0_fast(x.x) + focal0_fast(x.y) +
                  focal0_fast(x.z) + focal0_fast(x.w);
        }
    } else {
        // ---- focal(x,0) sweep s2: 512 float4/block, 2/thread --------------
        int chunk = wid - NBLK_BOX - NBLK_S0 - NBLK_S1;
        const int hw4 = 400, hw = 1600;
        int j0 = chunk * 512 + threadIdx.x;
        #pragma unroll
        for (int r = 0; r < 2; ++r) {
            int idx = j0 + r * 256;
            int b = idx / hw4;
            int pos4 = idx - b * hw4;
            const float4* src = reinterpret_cast<const float4*>(
                p2 + (size_t)b * 18 * hw + (size_t)4 * hw);
            float4 x = src[pos4];
            v0 += focal0_fast(x.x) + focal0_fast(x.y) +
                  focal0_fast(x.z) + focal0_fast(x.w);
        }
    }

    // ---- block reduce, one coalesced float4 store (NO global atomics) -----
    for (int off = 32; off; off >>= 1) {
        v0 += __shfl_down(v0, off);
        v1 += __shfl_down(v1, off);
        v2 += __shfl_down(v2, off);
    }
    if ((threadIdx.x & 63) == 0) {
        sm0[threadIdx.x >> 6] = v0;
        sm1[threadIdx.x >> 6] = v1;
        sm2[threadIdx.x >> 6] = v2;
    }
    __syncthreads();
    if (threadIdx.x == 0) {
        float4 slot;
        slot.x = sm0[0] + sm0[1] + sm0[2] + sm0[3];
        slot.y = sm1[0] + sm1[1] + sm1[2] + sm1[3];
        slot.z = sm2[0] + sm2[1] + sm2[2] + sm2[3];
        slot.w = 0.0f;
        ws4[wid] = slot;
    }
}

__global__ void __launch_bounds__(256) fnl_finalize(
    const float4* __restrict__ ws4, float* __restrict__ out) {
    // acc layout: [s*4 + {0:focal,1:box,2:cls,3:corr}]
    float a[12];
    #pragma unroll
    for (int j = 0; j < 12; ++j) a[j] = 0.0f;

    int i = threadIdx.x;
    if (i < NWORK) {
        float4 v = ws4[i];                            // coalesced 2.4KB read
        if (i < NBLK_BOX) {
            int s = i >> 1;
            a[s * 4 + 1] += v.x;
            a[s * 4 + 3] += v.y;
            a[s * 4 + 2] += v.z;
        } else if (i < NBLK_BOX + NBLK_S0) {
            a[0 * 4 + 0] += v.x;
        } else if (i < NBLK_BOX + NBLK_S0 + NBLK_S1) {
            a[1 * 4 + 0] += v.x;
        } else {
            a[2 * 4 + 0] += v.x;
        }
    }

    __shared__ float red[12];
    if (threadIdx.x < 12) red[threadIdx.x] = 0.0f;
    __syncthreads();
    #pragma unroll
    for (int j = 0; j < 12; ++j) {
        float v = a[j];
        for (int off = 32; off; off >>= 1) v += __shfl_down(v, off);
        if ((threadIdx.x & 63) == 0) atomicAdd(&red[j], v);   // LDS atomic
    }
    __syncthreads();

    if (threadIdx.x == 0) {
        const float cells[3] = {819200.0f, 204800.0f, 51200.0f};
        const float npos = 512.0f;
        float lb = 0.0f, lo = 0.0f, lc = 0.0f;
        for (int s = 0; s < 3; ++s) {
            lb += red[s * 4 + 1] / npos;
            lo += (red[s * 4 + 0] + red[s * 4 + 3]) / cells[s];
            lc += red[s * 4 + 2] / (npos * 13.0f);
        }
        out[0] = 5.0f * lb + 1.0f * lo + 0.5f * lc;
        out[1] = lb;
        out[2] = lo;
        out[3] = lc;
    }
}

extern "C" void kernel_launch(void* const* d_in, const int* in_sizes, int n_in,
                              void* d_out, int out_size, void* d_ws, size_t ws_size,
                              hipStream_t stream) {
    const float* p0 = (const float*)d_in[0];
    const float* p1 = (const float*)d_in[1];
    const float* p2 = (const float*)d_in[2];
    const float* tg = (const float*)d_in[3];
    float4* ws4 = (float4*)d_ws;
    float* out = (float*)d_out;

    fnl_main<<<NWORK, 256, 0, stream>>>(p0, p1, p2, tg, ws4);
    fnl_finalize<<<1, 256, 0, stream>>>(ws4, out);
}